// Round 6
// baseline (212.988 us; speedup 1.0000x reference)
//
#include <hip/hip_runtime.h>

#define BB 128
#define II 512
#define HH 256
#define OO 32
#define FF 16
#define OF 512
#define CI 64          // i-rows per route block
#define NP 8           // partials per b (II / CI)
#define XTSTR 260      // prep LDS transpose row stride (ushorts)
#define CSTR 72        // c2 LDS row stride (ushorts, 144 B, 16B-mult)

typedef __attribute__((ext_vector_type(8))) short short8;   // 8 bf16
typedef __attribute__((ext_vector_type(4))) float floatx4;  // MFMA C/D

__device__ __forceinline__ ushort f2bf(float f) {           // RTN-even
  unsigned u = __float_as_uint(f);
  u += 0x7FFFu + ((u >> 16) & 1u);
  return (ushort)(u >> 16);
}
__device__ __forceinline__ float bf2f(ushort u) {
  return __uint_as_float(((unsigned)u) << 16);
}

// ---------- Kernel 1: x -> bf16 (both layouts) + per-chunk column sums -----
// grid = B*NP (1024), block = 256. Each block owns a [64 i][256 h] tile.
__global__ __launch_bounds__(256) void k_prep(
    const float* __restrict__ x, ushort* __restrict__ x16,
    ushort* __restrict__ xT16, float* __restrict__ xsum_part) {
  __shared__ ushort xt[CI * XTSTR];     // 33.3 KB
  __shared__ float4 red[4][64];
  int t = threadIdx.x;
  int blk = blockIdx.x;                 // b*8 + p
  int c4 = t & 63, grp = t >> 6;
  const float* xg = x + (size_t)blk * CI * HH;
  ushort* x16g = x16 + (size_t)blk * CI * HH;
  float4 sum = make_float4(0.f, 0.f, 0.f, 0.f);
#pragma unroll
  for (int j = 0; j < 16; ++j) {
    int row = j * 4 + grp;
    float4 v4 = *(const float4*)(xg + (size_t)row * HH + c4 * 4);
    sum.x += v4.x; sum.y += v4.y; sum.z += v4.z; sum.w += v4.w;
    ushort4 u;
    u.x = f2bf(v4.x); u.y = f2bf(v4.y); u.z = f2bf(v4.z); u.w = f2bf(v4.w);
    *(ushort4*)&xt[row * XTSTR + c4 * 4] = u;
    *(ushort4*)&x16g[(size_t)row * HH + c4 * 4] = u;     // coalesced 512B
  }
  red[grp][c4] = sum;
  __syncthreads();
  if (t < 64) {
    float4 s = red[0][t];
    float4 s1 = red[1][t], s2 = red[2][t], s3 = red[3][t];
    s.x += s1.x + s2.x + s3.x; s.y += s1.y + s2.y + s3.y;
    s.z += s1.z + s2.z + s3.z; s.w += s1.w + s2.w + s3.w;
    *(float4*)&xsum_part[(size_t)blk * HH + t * 4] = s;
  }
  // transpose: thread = h, gather 64 i (paired lanes share LDS words -> clean)
  ushort* xtg = xT16 + (size_t)blk * HH * CI + (size_t)t * CI;
#pragma unroll
  for (int ch = 0; ch < 8; ++ch) {
    ushort4 a, bq;
    a.x = xt[(ch * 8 + 0) * XTSTR + t]; a.y = xt[(ch * 8 + 1) * XTSTR + t];
    a.z = xt[(ch * 8 + 2) * XTSTR + t]; a.w = xt[(ch * 8 + 3) * XTSTR + t];
    bq.x = xt[(ch * 8 + 4) * XTSTR + t]; bq.y = xt[(ch * 8 + 5) * XTSTR + t];
    bq.z = xt[(ch * 8 + 6) * XTSTR + t]; bq.w = xt[(ch * 8 + 7) * XTSTR + t];
    *(ushort4*)(xtg + ch * 8) = a;
    *(ushort4*)(xtg + ch * 8 + 4) = bq;
  }
}

// ---------- Kernel 2: v1 = squash(xsum @ W / 32), then wvT16 ---------------
// grid = B, block = 512
__global__ __launch_bounds__(512) void k_v1(
    const float* __restrict__ xsum_part, const float* __restrict__ W,
    ushort* __restrict__ wvT16) {
  __shared__ float xs[HH];
  __shared__ float vs2[OF];
  int t = threadIdx.x;
  int b = blockIdx.x;
  if (t < HH) {
    float a = 0.f;
#pragma unroll
    for (int ch = 0; ch < 8; ++ch) a += xsum_part[((size_t)b * 8 + ch) * HH + t];
    xs[t] = a;
  }
  __syncthreads();
  float acc = 0.f;
#pragma unroll 4
  for (int h = 0; h < HH; ++h)
    acc += xs[h] * W[(size_t)h * OF + t];
  acc *= (1.0f / 32.0f);
  float n2 = acc * acc;
#pragma unroll
  for (int mask = 1; mask < 16; mask <<= 1) n2 += __shfl_xor(n2, mask);
  float scale = sqrtf(n2) / (1.f + n2);
  vs2[t] = acc * scale;
  __syncthreads();
  // wvT[o][h] = sum_f W[h][o*16+f] * v[o][f]
  int h = t & 255, og = t >> 8;
  const float* wb = W + (size_t)h * OF;
#pragma unroll 2
  for (int j = 0; j < 16; ++j) {
    int o = og * 16 + j;
    const float4* wp = (const float4*)(wb + o * FF);
    const float4* vp = (const float4*)(vs2 + o * FF);
    float a = 0.f;
#pragma unroll
    for (int q = 0; q < 4; ++q) {
      float4 w4 = wp[q], v4 = vp[q];
      a += w4.x * v4.x + w4.y * v4.y + w4.z * v4.z + w4.w * v4.w;
    }
    wvT16[((size_t)b * OO + o) * HH + h] = f2bf(a);
  }
}

// ---------- Kernel 3: all-MFMA route: logits -> reg softmax -> cx ----------
// grid = B*NP (1024), block = 256 (4 waves), LDS 4.6 KB
__global__ __launch_bounds__(256, 4) void k_route(
    const ushort* __restrict__ x16, const ushort* __restrict__ xT16,
    const ushort* __restrict__ wvT16, ushort* __restrict__ cxp16) {
  __shared__ ushort c2[OO * CSTR];      // c in [o][i] bf16
  int t = threadIdx.x;
  int blk = blockIdx.x;
  int b = blk >> 3;
  int lane = t & 63, w = t >> 6;        // w = i-tile of this wave
  int l16 = lane & 15, quad = lane >> 4;

  // ---- GEMM1: D[m=i][n=o] = x16 . wvT^T  (K = h = 256, 8 steps) ----
  const ushort* xrow = x16 + ((size_t)blk * CI + w * 16 + l16) * HH + quad * 8;
  const ushort* wv0 = wvT16 + ((size_t)b * OO + l16) * HH + quad * 8;
  const ushort* wv1 = wv0 + 16 * HH;
  floatx4 acc0 = {0.f, 0.f, 0.f, 0.f}, acc1 = {0.f, 0.f, 0.f, 0.f};
#pragma unroll
  for (int ks = 0; ks < 8; ++ks) {
    short8 af = *(const short8*)(xrow + ks * 32);
    short8 b0 = *(const short8*)(wv0 + ks * 32);
    short8 b1 = *(const short8*)(wv1 + ks * 32);
    acc0 = __builtin_amdgcn_mfma_f32_16x16x32_bf16(af, b0, acc0, 0, 0, 0);
    acc1 = __builtin_amdgcn_mfma_f32_16x16x32_bf16(af, b1, acc1, 0, 0, 0);
  }
  // ---- softmax over o, fully in-register (rows i = quad*4+r, col o = l16) --
#pragma unroll
  for (int r = 0; r < 4; ++r) {
    float a0 = acc0[r], a1 = acc1[r];
    float m = fmaxf(a0, a1);
#pragma unroll
    for (int mask = 1; mask < 16; mask <<= 1) m = fmaxf(m, __shfl_xor(m, mask));
    float e0 = __expf(a0 - m), e1 = __expf(a1 - m);
    float s = e0 + e1;
#pragma unroll
    for (int mask = 1; mask < 16; mask <<= 1) s += __shfl_xor(s, mask);
    float inv = 1.f / s;
    int il = w * 16 + quad * 4 + r;
    c2[l16 * CSTR + il] = f2bf(e0 * inv);
    c2[(16 + l16) * CSTR + il] = f2bf(e1 * inv);
  }
  __syncthreads();

  // ---- phase 3: D[m=o][n=h] = c . xT^T  (K = i = 64, 2 steps) ----
  short8 caf[2][2];
#pragma unroll
  for (int mt = 0; mt < 2; ++mt)
#pragma unroll
    for (int ks = 0; ks < 2; ++ks)
      caf[mt][ks] = *(const short8*)&c2[(mt * 16 + l16) * CSTR + ks * 32 + quad * 8];
  const ushort* xtp = xT16 + (size_t)blk * HH * CI;
  ushort* outp0 = cxp16 + (size_t)blk * OO * HH;
#pragma unroll
  for (int hi = 0; hi < 4; ++hi) {
    int ht = w * 4 + hi;
    const ushort* xtr = xtp + (size_t)(ht * 16 + l16) * CI + quad * 8;
    floatx4 d0 = {0.f, 0.f, 0.f, 0.f}, d1 = {0.f, 0.f, 0.f, 0.f};
#pragma unroll
    for (int ks = 0; ks < 2; ++ks) {
      short8 bf = *(const short8*)(xtr + ks * 32);
      d0 = __builtin_amdgcn_mfma_f32_16x16x32_bf16(caf[0][ks], bf, d0, 0, 0, 0);
      d1 = __builtin_amdgcn_mfma_f32_16x16x32_bf16(caf[1][ks], bf, d1, 0, 0, 0);
    }
    ushort* outp = outp0 + ht * 16 + l16;
#pragma unroll
    for (int r = 0; r < 4; ++r) {
      outp[(size_t)(quad * 4 + r) * HH] = f2bf(d0[r]);
      outp[(size_t)(16 + quad * 4 + r) * HH] = f2bf(d1[r]);
    }
  }
}

// ---------- Kernel 4: reduce partials, v = squash(cx @ W), emit wvT/out ----
// grid = B*O (4096), block = 256
__global__ __launch_bounds__(256) void k_v2(
    const ushort* __restrict__ cxp16, const float* __restrict__ W,
    ushort* __restrict__ wvT16, float* __restrict__ out, int final_) {
  __shared__ float cxs[HH];
  __shared__ float red[4][16];
  __shared__ float vres[FF];
  int t = threadIdx.x;
  int blk = blockIdx.x;                 // b*32 + o
  int b = blk >> 5, o = blk & 31;
  {
    const ushort* cp = cxp16 + (((size_t)b * NP) * OO + o) * HH + t;
    float a = 0.f;
#pragma unroll
    for (int p = 0; p < NP; ++p) a += bf2f(cp[(size_t)p * OO * HH]);
    cxs[t] = a;
  }
  __syncthreads();
  int f = t & 15, hq = t >> 4;
  const float* wp = W + (size_t)hq * 16 * OF + o * FF + f;
  float acc = 0.f;
#pragma unroll
  for (int j = 0; j < 16; ++j)
    acc += cxs[hq * 16 + j] * wp[(size_t)j * OF];
  acc += __shfl_xor(acc, 16);
  acc += __shfl_xor(acc, 32);
  if ((t & 63) < 16) red[t >> 6][f] = acc;
  __syncthreads();
  if (t < 16) {
    float a = red[0][t] + red[1][t] + red[2][t] + red[3][t];
    float n2 = a * a;
#pragma unroll
    for (int mask = 1; mask < 16; mask <<= 1) n2 += __shfl_xor(n2, mask);
    float scale = sqrtf(n2) / (1.f + n2);
    float res = a * scale;
    if (final_) out[(size_t)blk * FF + t] = res;
    else vres[t] = res;
  }
  if (!final_) {
    __syncthreads();
    // wvT[o][h] for next iteration: h = t
    const float4* wq = (const float4*)(W + (size_t)t * OF + o * FF);
    const float4* vp = (const float4*)vres;
    float a = 0.f;
#pragma unroll
    for (int q = 0; q < 4; ++q) {
      float4 w4 = wq[q], v4 = vp[q];
      a += w4.x * v4.x + w4.y * v4.y + w4.z * v4.z + w4.w * v4.w;
    }
    wvT16[((size_t)b * OO + o) * HH + t] = f2bf(a);
  }
}

extern "C" void kernel_launch(void* const* d_in, const int* in_sizes, int n_in,
                              void* d_out, int out_size, void* d_ws, size_t ws_size,
                              hipStream_t stream) {
  const float* x = (const float*)d_in[0];  // [128,512,256] fp32
  const float* W = (const float*)d_in[1];  // [1,256,512]   fp32
  float* out = (float*)d_out;              // [128,32,16]   fp32
  float* ws = (float*)d_ws;
  // workspace (float offsets), total ~87 MiB
  float*  xsum_part = ws;                           // 262144 floats
  ushort* wvT16 = (ushort*)(ws + 262144);           // 1,048,576 ushorts
  ushort* x16   = (ushort*)(ws + 786432);           // 16,777,216 ushorts
  ushort* xT16  = (ushort*)(ws + 9175040);          // 16,777,216 ushorts
  ushort* cxp16 = (ushort*)(ws + 17563648);         // 8,388,608 ushorts

  k_prep<<<BB * NP, 256, 0, stream>>>(x, x16, xT16, xsum_part);
  k_v1<<<BB, 512, 0, stream>>>(xsum_part, W, wvT16);
  for (int it = 0; it < 2; ++it) {
    k_route<<<BB * NP, 256, 0, stream>>>(x16, xT16, wvT16, cxp16);
    k_v2<<<BB * OO, 256, 0, stream>>>(cxp16, W, wvT16, out, it == 1);
  }
}

// Round 7
// 181.663 us; speedup vs baseline: 1.1724x; 1.1724x over previous
//
#include <hip/hip_runtime.h>

#define BB 128
#define II 512
#define HH 256
#define OO 32
#define FF 16
#define OF 512
#define CI 64          // i-rows per route block
#define NP 8           // partials per b (II / CI)
#define XTSTR 260      // prep LDS transpose row stride (ushorts)
#define CSTR 72        // c2 LDS row stride (ushorts, 144 B, 16B-mult)

typedef __attribute__((ext_vector_type(8))) short short8;   // 8 bf16
typedef __attribute__((ext_vector_type(4))) float floatx4;  // MFMA C/D

__device__ __forceinline__ ushort f2bf(float f) {           // RTN-even
  unsigned u = __float_as_uint(f);
  u += 0x7FFFu + ((u >> 16) & 1u);
  return (ushort)(u >> 16);
}
__device__ __forceinline__ float bf2f(ushort u) {
  return __uint_as_float(((unsigned)u) << 16);
}

// ---------- Kernel 1: x -> bf16 (both layouts) + per-chunk column sums -----
// grid = B*NP (1024), block = 256. Each block owns a [64 i][256 h] tile.
__global__ __launch_bounds__(256) void k_prep(
    const float* __restrict__ x, ushort* __restrict__ x16,
    ushort* __restrict__ xT16, float* __restrict__ xsum_part) {
  __shared__ ushort xt[CI * XTSTR];     // 33.3 KB
  __shared__ float4 red[4][64];
  int t = threadIdx.x;
  int blk = blockIdx.x;                 // b*8 + p
  int c4 = t & 63, grp = t >> 6;
  const float* xg = x + (size_t)blk * CI * HH;
  ushort* x16g = x16 + (size_t)blk * CI * HH;
  float4 sum = make_float4(0.f, 0.f, 0.f, 0.f);
#pragma unroll
  for (int j = 0; j < 16; ++j) {
    int row = j * 4 + grp;
    float4 v4 = *(const float4*)(xg + (size_t)row * HH + c4 * 4);
    sum.x += v4.x; sum.y += v4.y; sum.z += v4.z; sum.w += v4.w;
    ushort4 u;
    u.x = f2bf(v4.x); u.y = f2bf(v4.y); u.z = f2bf(v4.z); u.w = f2bf(v4.w);
    *(ushort4*)&xt[row * XTSTR + c4 * 4] = u;
    *(ushort4*)&x16g[(size_t)row * HH + c4 * 4] = u;     // coalesced 512B
  }
  red[grp][c4] = sum;
  __syncthreads();
  if (t < 64) {
    float4 s = red[0][t];
    float4 s1 = red[1][t], s2 = red[2][t], s3 = red[3][t];
    s.x += s1.x + s2.x + s3.x; s.y += s1.y + s2.y + s3.y;
    s.z += s1.z + s2.z + s3.z; s.w += s1.w + s2.w + s3.w;
    *(float4*)&xsum_part[(size_t)blk * HH + t * 4] = s;
  }
  // transpose: thread = h, gather 64 i (each 128B xT16 line fully written by one thread)
  ushort* xtg = xT16 + (size_t)blk * HH * CI + (size_t)t * CI;
#pragma unroll
  for (int ch = 0; ch < 8; ++ch) {
    ushort4 a, bq;
    a.x = xt[(ch * 8 + 0) * XTSTR + t]; a.y = xt[(ch * 8 + 1) * XTSTR + t];
    a.z = xt[(ch * 8 + 2) * XTSTR + t]; a.w = xt[(ch * 8 + 3) * XTSTR + t];
    bq.x = xt[(ch * 8 + 4) * XTSTR + t]; bq.y = xt[(ch * 8 + 5) * XTSTR + t];
    bq.z = xt[(ch * 8 + 6) * XTSTR + t]; bq.w = xt[(ch * 8 + 7) * XTSTR + t];
    *(ushort4*)(xtg + ch * 8) = a;
    *(ushort4*)(xtg + ch * 8 + 4) = bq;
  }
}

// ---------- Kernel 2: v1 = squash(xsum @ W / 32) -> wvT16 (k_v2 shape) -----
// grid = B*O (4096), block = 256
__global__ __launch_bounds__(256) void k_v1(
    const float* __restrict__ xsum_part, const float* __restrict__ W,
    ushort* __restrict__ wvT16) {
  __shared__ float cxs[HH];
  __shared__ float red[4][16];
  __shared__ float vres[FF];
  int t = threadIdx.x;
  int blk = blockIdx.x;                 // b*32 + o
  int b = blk >> 5, o = blk & 31;
  {
    const float* cp = xsum_part + (size_t)b * NP * HH + t;   // coalesced, t = h
    float a = 0.f;
#pragma unroll
    for (int p = 0; p < NP; ++p) a += cp[(size_t)p * HH];
    cxs[t] = a * (1.0f / 32.0f);
  }
  __syncthreads();
  int f = t & 15, hq = t >> 4;
  const float* wp = W + (size_t)hq * 16 * OF + o * FF + f;
  float acc = 0.f;
#pragma unroll
  for (int j = 0; j < 16; ++j)
    acc += cxs[hq * 16 + j] * wp[(size_t)j * OF];
  acc += __shfl_xor(acc, 16);
  acc += __shfl_xor(acc, 32);
  if ((t & 63) < 16) red[t >> 6][f] = acc;
  __syncthreads();
  if (t < 16) {
    float a = red[0][t] + red[1][t] + red[2][t] + red[3][t];
    float n2 = a * a;
#pragma unroll
    for (int mask = 1; mask < 16; mask <<= 1) n2 += __shfl_xor(n2, mask);
    float scale = sqrtf(n2) / (1.f + n2);
    vres[t] = a * scale;
  }
  __syncthreads();
  // wvT[o][h] emit: t = h
  const float4* wq = (const float4*)(W + (size_t)t * OF + o * FF);
  const float4* vp = (const float4*)vres;
  float a = 0.f;
#pragma unroll
  for (int q = 0; q < 4; ++q) {
    float4 w4 = wq[q], v4 = vp[q];
    a += w4.x * v4.x + w4.y * v4.y + w4.z * v4.z + w4.w * v4.w;
  }
  wvT16[((size_t)b * OO + o) * HH + t] = f2bf(a);
}

// ---------- Kernel 3: all-MFMA route: logits -> reg softmax -> cx ----------
// grid = B*NP (1024), block = 256 (4 waves), LDS 4.6 KB
__global__ __launch_bounds__(256, 4) void k_route(
    const ushort* __restrict__ x16, const ushort* __restrict__ xT16,
    const ushort* __restrict__ wvT16, ushort* __restrict__ cxp16) {
  __shared__ ushort c2[OO * CSTR];      // c in [o][i] bf16
  int t = threadIdx.x;
  int blk = blockIdx.x;
  int b = blk >> 3;
  int lane = t & 63, w = t >> 6;        // w = i-tile of this wave
  int l16 = lane & 15, quad = lane >> 4;

  // ---- GEMM1: D[m=i][n=o] = x16 . wvT^T  (K = h = 256, 8 steps) ----
  const ushort* xrow = x16 + ((size_t)blk * CI + w * 16 + l16) * HH + quad * 8;
  const ushort* wv0 = wvT16 + ((size_t)b * OO + l16) * HH + quad * 8;
  const ushort* wv1 = wv0 + 16 * HH;
  floatx4 acc0 = {0.f, 0.f, 0.f, 0.f}, acc1 = {0.f, 0.f, 0.f, 0.f};
#pragma unroll
  for (int ks = 0; ks < 8; ++ks) {
    short8 af = *(const short8*)(xrow + ks * 32);
    short8 b0 = *(const short8*)(wv0 + ks * 32);
    short8 b1 = *(const short8*)(wv1 + ks * 32);
    acc0 = __builtin_amdgcn_mfma_f32_16x16x32_bf16(af, b0, acc0, 0, 0, 0);
    acc1 = __builtin_amdgcn_mfma_f32_16x16x32_bf16(af, b1, acc1, 0, 0, 0);
  }
  // ---- softmax over o, fully in-register (rows i = quad*4+r, col o = l16) --
#pragma unroll
  for (int r = 0; r < 4; ++r) {
    float a0 = acc0[r], a1 = acc1[r];
    float m = fmaxf(a0, a1);
#pragma unroll
    for (int mask = 1; mask < 16; mask <<= 1) m = fmaxf(m, __shfl_xor(m, mask));
    float e0 = __expf(a0 - m), e1 = __expf(a1 - m);
    float s = e0 + e1;
#pragma unroll
    for (int mask = 1; mask < 16; mask <<= 1) s += __shfl_xor(s, mask);
    float inv = 1.f / s;
    int il = w * 16 + quad * 4 + r;
    c2[l16 * CSTR + il] = f2bf(e0 * inv);
    c2[(16 + l16) * CSTR + il] = f2bf(e1 * inv);
  }
  __syncthreads();

  // ---- phase 3: D[m=o][n=h] = c . xT^T  (K = i = 64, 2 steps) ----
  short8 caf[2][2];
#pragma unroll
  for (int mt = 0; mt < 2; ++mt)
#pragma unroll
    for (int ks = 0; ks < 2; ++ks)
      caf[mt][ks] = *(const short8*)&c2[(mt * 16 + l16) * CSTR + ks * 32 + quad * 8];
  const ushort* xtp = xT16 + (size_t)blk * HH * CI;
  ushort* outp0 = cxp16 + (size_t)blk * OO * HH;
#pragma unroll
  for (int hi = 0; hi < 4; ++hi) {
    int ht = w * 4 + hi;
    const ushort* xtr = xtp + (size_t)(ht * 16 + l16) * CI + quad * 8;
    floatx4 d0 = {0.f, 0.f, 0.f, 0.f}, d1 = {0.f, 0.f, 0.f, 0.f};
#pragma unroll
    for (int ks = 0; ks < 2; ++ks) {
      short8 bf = *(const short8*)(xtr + ks * 32);
      d0 = __builtin_amdgcn_mfma_f32_16x16x32_bf16(caf[0][ks], bf, d0, 0, 0, 0);
      d1 = __builtin_amdgcn_mfma_f32_16x16x32_bf16(caf[1][ks], bf, d1, 0, 0, 0);
    }
    ushort* outp = outp0 + ht * 16 + l16;
#pragma unroll
    for (int r = 0; r < 4; ++r) {
      outp[(size_t)(quad * 4 + r) * HH] = f2bf(d0[r]);
      outp[(size_t)(16 + quad * 4 + r) * HH] = f2bf(d1[r]);
    }
  }
}

// ---------- Kernel 4: reduce partials, v = squash(cx @ W), emit wvT/out ----
// grid = B*O (4096), block = 256
__global__ __launch_bounds__(256) void k_v2(
    const ushort* __restrict__ cxp16, const float* __restrict__ W,
    ushort* __restrict__ wvT16, float* __restrict__ out, int final_) {
  __shared__ float cxs[HH];
  __shared__ float red[4][16];
  __shared__ float vres[FF];
  int t = threadIdx.x;
  int blk = blockIdx.x;                 // b*32 + o
  int b = blk >> 5, o = blk & 31;
  {
    const ushort* cp = cxp16 + (((size_t)b * NP) * OO + o) * HH + t;
    float a = 0.f;
#pragma unroll
    for (int p = 0; p < NP; ++p) a += bf2f(cp[(size_t)p * OO * HH]);
    cxs[t] = a;
  }
  __syncthreads();
  int f = t & 15, hq = t >> 4;
  const float* wp = W + (size_t)hq * 16 * OF + o * FF + f;
  float acc = 0.f;
#pragma unroll
  for (int j = 0; j < 16; ++j)
    acc += cxs[hq * 16 + j] * wp[(size_t)j * OF];
  acc += __shfl_xor(acc, 16);
  acc += __shfl_xor(acc, 32);
  if ((t & 63) < 16) red[t >> 6][f] = acc;
  __syncthreads();
  if (t < 16) {
    float a = red[0][t] + red[1][t] + red[2][t] + red[3][t];
    float n2 = a * a;
#pragma unroll
    for (int mask = 1; mask < 16; mask <<= 1) n2 += __shfl_xor(n2, mask);
    float scale = sqrtf(n2) / (1.f + n2);
    float res = a * scale;
    if (final_) out[(size_t)blk * FF + t] = res;
    else vres[t] = res;
  }
  if (!final_) {
    __syncthreads();
    // wvT[o][h] for next iteration: h = t
    const float4* wq = (const float4*)(W + (size_t)t * OF + o * FF);
    const float4* vp = (const float4*)vres;
    float a = 0.f;
#pragma unroll
    for (int q = 0; q < 4; ++q) {
      float4 w4 = wq[q], v4 = vp[q];
      a += w4.x * v4.x + w4.y * v4.y + w4.z * v4.z + w4.w * v4.w;
    }
    wvT16[((size_t)b * OO + o) * HH + t] = f2bf(a);
  }
}

extern "C" void kernel_launch(void* const* d_in, const int* in_sizes, int n_in,
                              void* d_out, int out_size, void* d_ws, size_t ws_size,
                              hipStream_t stream) {
  const float* x = (const float*)d_in[0];  // [128,512,256] fp32
  const float* W = (const float*)d_in[1];  // [1,256,512]   fp32
  float* out = (float*)d_out;              // [128,32,16]   fp32
  float* ws = (float*)d_ws;
  // workspace (float offsets), total ~87 MiB
  float*  xsum_part = ws;                           // 262144 floats
  ushort* wvT16 = (ushort*)(ws + 262144);           // 1,048,576 ushorts
  ushort* x16   = (ushort*)(ws + 786432);           // 16,777,216 ushorts
  ushort* xT16  = (ushort*)(ws + 9175040);          // 16,777,216 ushorts
  ushort* cxp16 = (ushort*)(ws + 17563648);         // 8,388,608 ushorts

  k_prep<<<BB * NP, 256, 0, stream>>>(x, x16, xT16, xsum_part);
  k_v1<<<BB * OO, 256, 0, stream>>>(xsum_part, W, wvT16);
  for (int it = 0; it < 2; ++it) {
    k_route<<<BB * NP, 256, 0, stream>>>(x16, xT16, wvT16, cxp16);
    k_v2<<<BB * OO, 256, 0, stream>>>(cxp16, W, wvT16, out, it == 1);
  }
}